// Round 12
// baseline (43.930 us; speedup 1.0000x reference)
//
#include <hip/hip_runtime.h>
#include <math.h>

typedef __bf16 bf16x8 __attribute__((ext_vector_type(8)));
typedef float f32x4 __attribute__((ext_vector_type(4)));

#define B_SZ 512
#define IN_F 342
#define HID  512
#define OUT_F 311

// ---------------------------------------------------------------------------
// Weight transpose+convert+interleave (one 64x64 tile per call):
//  JOB0: T0[h*4+c][i] = W0[c][i][h]  (2048 x 384, i>=342 -> 0)
//  JOB1: T1[h*4+c][k] = W1[c][k][h]  (2048 x 512)
//  JOB2: T2[n*4+c][k] = W2[c][k][n]  (1280 x 512, n>=311 -> 0)
// Interleaved rows n'=h*4+c put the 4 c-slices of an output in one MFMA
// lane-quad, so the coefficient reduction is 2 shfl_xor in the GEMM epilogue.
// ---------------------------------------------------------------------------
template <int JOB>
__device__ void wt_transpose(const float* __restrict__ W, __bf16* __restrict__ T,
                             int t) {
  constexpr int KP   = (JOB == 0) ? 384 : 512;   // dest row length (padded k)
  constexpr int KWF  = (JOB == 0) ? IN_F : HID;  // W k extent
  constexpr int NC   = (JOB == 2) ? OUT_F : HID; // W col extent
  constexpr int NSUB = (JOB == 2) ? 320 : 512;   // dest rows per c (pre-ilv)
  constexpr int KT   = KP / 64;
  const int r0 = (t / KT) * 64, k0 = (t % KT) * 64;
  __shared__ __bf16 tile[64][66];
  const int tid = threadIdx.x;
  const int rl = tid & 63;
  const int c = r0 / NSUB;          // uniform per tile (64 | NSUB)
  const int nbase = r0 - c * NSUB;
#pragma unroll
  for (int jj = 0; jj < 16; ++jj) {
    int kl = (tid >> 6) + jj * 4;
    int k = k0 + kl;
    int n = nbase + rl;
    float v = 0.0f;
    if ((JOB != 0 || k < KWF) && (JOB != 2 || n < NC))
      v = W[((size_t)c * KWF + k) * NC + n];
    tile[rl][kl] = (__bf16)v;
  }
  __syncthreads();
  int row = tid >> 2, o0 = (tid & 3) * 16;
  bf16x8 v0 = *(const bf16x8*)&tile[row][o0];
  bf16x8 v1 = *(const bf16x8*)&tile[row][o0 + 8];
  int g = (nbase + row) * 4 + c;    // interleaved dest row
  __bf16* dst = T + (size_t)g * KP + k0 + o0;
  *(bf16x8*)dst = v0;
  *(bf16x8*)(dst + 8) = v1;
}

// ---------------------------------------------------------------------------
// Streaming bf16 MFMA GEMM (R11 inner loop, M-tile 32) + in-register
// quad-reduce epilogue (R9-validated). A: M x KA bf16; BT: interleaved
// n' x KA bf16 (k-major), fully padded. Block (nx,my): 32x64 tile, full K
// (T=6 or 8), 2-deep statically-named reg prefetch. Epilogue:
// v = cf[m][c]*(acc + bias[c][hn]); shfl_xor(1,2) sums quad over c;
// LAYER<2: ELU -> bf16 E[m][hn]; LAYER==2: fp32 out[m][n], n<311.
// ---------------------------------------------------------------------------
template <int LAYER>
__device__ void gemm_body(int nx, int my, const __bf16* __restrict__ A,
                          const __bf16* __restrict__ BT,
                          const float* __restrict__ bias,
                          const float* __restrict__ coef,
                          void* __restrict__ outv) {
  constexpr int KA = (LAYER == 0) ? 384 : 512;
  constexpr int T = KA / 64;        // 6 or 8 (even)
  constexpr int LDT = 72;
  __shared__ __bf16 Als[32 * LDT];
  __shared__ __bf16 Bls[64 * LDT];

  const int tid = threadIdx.x;
  const int l = tid & 63;
  const int wave = tid >> 6;
  const int wm = wave >> 1, wn = wave & 1;
  const int lr = l & 15, lk = l >> 4;
  const int m0 = my * 32;
  const int n0 = nx * 64;

  const int ar = tid >> 3, ao = tid & 7;        // A: row 0..31, octet 0..7
  const int br = tid >> 2, bo = (tid & 3) * 2;  // B: row 0..63, octets bo,bo+1

  const __bf16* Ap = A + (size_t)(m0 + ar) * KA + ao * 8;
  const __bf16* Bp = BT + (size_t)(n0 + br) * KA + bo * 8;

  bf16x8 a0_, b0_, b1_;   // phase 0
  bf16x8 a1_, b2_, b3_;   // phase 1
  f32x4 acc[2] = {};

  auto load0 = [&](int t) {
    a0_ = *(const bf16x8*)&Ap[t * 64];
    b0_ = *(const bf16x8*)&Bp[t * 64];
    b1_ = *(const bf16x8*)&Bp[t * 64 + 8];
  };
  auto load1 = [&](int t) {
    a1_ = *(const bf16x8*)&Ap[t * 64];
    b2_ = *(const bf16x8*)&Bp[t * 64];
    b3_ = *(const bf16x8*)&Bp[t * 64 + 8];
  };
  auto store0 = [&]() {
    *(bf16x8*)&Als[ar * LDT + ao * 8] = a0_;
    *(bf16x8*)&Bls[br * LDT + bo * 8] = b0_;
    *(bf16x8*)&Bls[br * LDT + bo * 8 + 8] = b1_;
  };
  auto store1 = [&]() {
    *(bf16x8*)&Als[ar * LDT + ao * 8] = a1_;
    *(bf16x8*)&Bls[br * LDT + bo * 8] = b2_;
    *(bf16x8*)&Bls[br * LDT + bo * 8 + 8] = b3_;
  };
  auto compute = [&]() {
#pragma unroll
    for (int kk = 0; kk < 64; kk += 32) {
      bf16x8 af = *(const bf16x8*)&Als[(wm * 16 + lr) * LDT + kk + lk * 8];
      bf16x8 bg[2];
#pragma unroll
      for (int j = 0; j < 2; ++j)
        bg[j] = *(const bf16x8*)&Bls[(wn * 32 + j * 16 + lr) * LDT + kk + lk * 8];
#pragma unroll
      for (int j = 0; j < 2; ++j)
        acc[j] = __builtin_amdgcn_mfma_f32_16x16x32_bf16(af, bg[j], acc[j], 0, 0, 0);
    }
  };

  load0(0);
  load1(1);
  for (int t = 0; t < T; t += 2) {
    __syncthreads();
    store0();
    __syncthreads();
    if (t + 2 < T) load0(t + 2);
    compute();
    __syncthreads();
    store1();
    __syncthreads();
    if (t + 3 < T) load1(t + 3);
    compute();
  }

  // ---- fused epilogue: quad holds the 4 c-partials of (gm, hn) ----
  const int cl = l & 3;
#pragma unroll
  for (int j = 0; j < 2; ++j) {
    int gnp = n0 + wn * 32 + j * 16 + lr;
    int hn = gnp >> 2;                       // h (L0/L1) or n (L2)
    float bv;
    if (LAYER == 2) bv = (hn < OUT_F) ? bias[cl * OUT_F + hn] : 0.0f;
    else            bv = bias[cl * HID + hn];
#pragma unroll
    for (int r = 0; r < 4; ++r) {
      int gm = m0 + wm * 16 + lk * 4 + r;
      float cf = coef[gm * 4 + cl];
      float v = cf * (acc[j][r] + bv);
      v += __shfl_xor(v, 1);
      v += __shfl_xor(v, 2);                 // quad sum over c
      if (LAYER == 2) {
        if (cl == 0 && hn < OUT_F)
          ((float*)outv)[(size_t)gm * OUT_F + hn] = v;
      } else {
        if (cl == 0) {
          float e = (v > 0.0f) ? v : expm1f(v);
          ((__bf16*)outv)[(size_t)gm * HID + hn] = (__bf16)e;
        }
      }
    }
  }
}

// ---------------------------------------------------------------------------
// setup (209 blocks): 0..191 WT0 transpose; 192..207 A0 = bf16(x) padded to
// 384; 208 coef[b][4] (Catmull-Rom weights permuted by i1).
// ---------------------------------------------------------------------------
__global__ __launch_bounds__(256) void setup_kernel(
    const float* __restrict__ p, const float* __restrict__ x,
    const float* __restrict__ W0, float* __restrict__ coef,
    __bf16* __restrict__ A0, __bf16* __restrict__ T0) {
  int bid = blockIdx.x, tid = threadIdx.x;
  if (bid < 192) { wt_transpose<0>(W0, T0, bid); return; }
  if (bid < 208) {
    int base = (bid - 192) * 32;
    for (int e = tid; e < 32 * 384; e += 256) {
      int m = base + (e >> 8) * 2 + ((e >> 7) & 1), i = e & 127;  // avoid div
      // simpler exact mapping:
      m = base + e / 384; i = e - (e / 384) * 384;
      A0[(size_t)m * 384 + i] =
          (i < IN_F) ? (__bf16)x[(size_t)m * IN_F + i] : (__bf16)0.0f;
    }
    return;
  }
  for (int b = tid; b < B_SZ; b += 256) {
    float p4 = p[b] * 4.0f;
    float mu = p4 - floorf(p4);
    int i1 = ((int)p4) & 3;
    float mu2 = mu * mu, mu3 = mu2 * mu;
    float c0 = -0.5f * mu3 + mu2 - 0.5f * mu;
    float c1 =  1.5f * mu3 - 2.5f * mu2 + 1.0f;
    float c2 = -1.5f * mu3 + 2.0f * mu2 + 0.5f * mu;
    float c3 =  0.5f * mu3 - 0.5f * mu2;
    float arr[4];
    arr[(i1 + 3) & 3] = c0;
    arr[i1]           = c1;
    arr[(i1 + 1) & 3] = c2;
    arr[(i1 + 2) & 3] = c3;
    coef[b * 4 + 0] = arr[0];
    coef[b * 4 + 1] = arr[1];
    coef[b * 4 + 2] = arr[2];
    coef[b * 4 + 3] = arr[3];
  }
}

// ---------------------------------------------------------------------------
// G0 (928 blocks): 0..511 layer-0 GEMM tiles; 512..767 WT1 transpose;
// 768..927 WT2 transpose (hidden under G0's idle CUs; ready for G1/G2 by
// kernel boundary).
// ---------------------------------------------------------------------------
__global__ __launch_bounds__(256) void g0_kernel(
    const __bf16* __restrict__ A0, const __bf16* __restrict__ T0,
    const float* __restrict__ W1, const float* __restrict__ W2,
    __bf16* __restrict__ T1, __bf16* __restrict__ T2,
    const float* __restrict__ b0, const float* __restrict__ coef,
    __bf16* __restrict__ E1) {
  int bid = blockIdx.x;
  if (bid < 512)      gemm_body<0>(bid & 31, bid >> 5, A0, T0, b0, coef, E1);
  else if (bid < 768) wt_transpose<1>(W1, T1, bid - 512);
  else                wt_transpose<2>(W2, T2, bid - 768);
}

__global__ __launch_bounds__(256) void g1_kernel(
    const __bf16* __restrict__ E1, const __bf16* __restrict__ T1,
    const float* __restrict__ b1, const float* __restrict__ coef,
    __bf16* __restrict__ E2) {
  gemm_body<1>(blockIdx.x, blockIdx.y, E1, T1, b1, coef, E2);
}

__global__ __launch_bounds__(256) void g2_kernel(
    const __bf16* __restrict__ E2, const __bf16* __restrict__ T2,
    const float* __restrict__ b2, const float* __restrict__ coef,
    float* __restrict__ out) {
  gemm_body<2>(blockIdx.x, blockIdx.y, E2, T2, b2, coef, out);
}

extern "C" void kernel_launch(void* const* d_in, const int* in_sizes, int n_in,
                              void* d_out, int out_size, void* d_ws, size_t ws_size,
                              hipStream_t stream) {
  const float* p  = (const float*)d_in[0];
  const float* x  = (const float*)d_in[1];
  const float* W0 = (const float*)d_in[2];
  const float* b0 = (const float*)d_in[3];
  const float* W1 = (const float*)d_in[4];
  const float* b1 = (const float*)d_in[5];
  const float* W2 = (const float*)d_in[6];
  const float* b2 = (const float*)d_in[7];
  float* out = (float*)d_out;

  char* w = (char*)d_ws;
  float*  coef = (float*)w;   w += 8192;
  __bf16* A0   = (__bf16*)w;  w += (size_t)B_SZ * 384 * 2;   // 384 KB
  __bf16* T0   = (__bf16*)w;  w += (size_t)2048 * 384 * 2;   // 1.5 MB
  __bf16* T1   = (__bf16*)w;  w += (size_t)2048 * 512 * 2;   // 2 MB
  __bf16* T2   = (__bf16*)w;  w += (size_t)1280 * 512 * 2;   // 1.25 MB
  __bf16* E1   = (__bf16*)w;  w += (size_t)B_SZ * HID * 2;   // 512 KB
  __bf16* E2   = (__bf16*)w;  w += (size_t)B_SZ * HID * 2;   // 512 KB

  setup_kernel<<<209, 256, 0, stream>>>(p, x, W0, coef, A0, T0);
  g0_kernel<<<928, 256, 0, stream>>>(A0, T0, W1, W2, T1, T2, b0, coef, E1);
  g1_kernel<<<dim3(32, 16), 256, 0, stream>>>(E1, T1, b1, coef, E2);
  g2_kernel<<<dim3(20, 16), 256, 0, stream>>>(E2, T2, b2, coef, out);
}